// Round 3
// baseline (391.496 us; speedup 1.0000x reference)
//
#include <hip/hip_runtime.h>
#include <math.h>

// HistogramBinningCalibrationByFeature
// d_out: [0..N) calibrated_prediction (f32) | [N..2N) bin ids (f32-encoded)
//
// R3: lane-interleaved layout. Each thread owns TWO 4-element groups at
//   e = blockBase + c*1024 + tid*4   (c = 0,1; block covers 2048 elements)
// so every float4/int4 stream load/store is wave-coalesced (16 lines/instr
// instead of 64). seg_len overlap (s[e+4]) comes from the next lane via
// __shfl; lane 63 does a 1-lane predicated load. Ratio table (fused
// (pos/num)*0.9995, NaN = invalid) lives in d_ws -> one random gather/elem.

constexpr int kNumBins     = 5000;
constexpr int kNumSegments = 42;
constexpr int kNumInterval = (kNumSegments + 1) * kNumBins;  // 215000

typedef float f32x4 __attribute__((ext_vector_type(4)));
typedef int   i32x4 __attribute__((ext_vector_type(4)));

__global__ __launch_bounds__(256) void ratio_kernel(
    const float* __restrict__ bin_pos,
    const float* __restrict__ bin_num,
    const float* __restrict__ pos_w,
    float*       __restrict__ ratio)   // [kNumInterval + 1]
{
    const int i = blockIdx.x * 256 + threadIdx.x;
    if (i < kNumInterval) {
        const float nm = bin_num[i];
        const float r = (nm > 0.0f) ? (bin_pos[i] / nm) * 0.9995f
                                    : __int_as_float(0x7FC00000);  // NaN
        ratio[i] = r;
    }
    if (i == 0) {
        ratio[kNumInterval] = (float)log((double)pos_w[0]);
    }
}

__device__ __forceinline__ void process4(
    const float* __restrict__ l, const int* __restrict__ s,
    const int*   __restrict__ seg_val, const float* __restrict__ ratio,
    float lpw, float* __restrict__ op, float* __restrict__ ob)
{
    const float kStep = 0.0002f;

    int ds[4];
    #pragma unroll
    for (int j = 0; j < 4; ++j) {
        int d = 0;
        if (s[j + 1] > s[j]) {                 // predicated gather
            const int sv = seg_val[s[j]] + 1;
            d = (sv > kNumSegments) ? 0 : sv;
        }
        ds[j] = d;
    }

    float p[4]; int bin[4];
    #pragma unroll
    for (int j = 0; j < 4; ++j) {
        const float x  = l[j] + lpw;
        const float pf = 1.0f / (1.0f + expf(-x));
        p[j]   = pf;
        bin[j] = (int)(ceilf(pf / kStep) - 1.0f) + ds[j] * kNumBins;
    }

    float r[4];
    #pragma unroll
    for (int j = 0; j < 4; ++j) {
        int idx = bin[j];
        idx = idx < 0 ? 0 : idx;
        idx = idx > (kNumInterval - 1) ? (kNumInterval - 1) : idx;
        r[j] = ratio[idx];                     // single random gather
    }

    #pragma unroll
    for (int j = 0; j < 4; ++j) {
        op[j] = (r[j] == r[j]) ? (r[j] + p[j] * 0.0005f) : p[j];
        ob[j] = (float)bin[j];
    }
}

__global__ __launch_bounds__(256) void hbc_lane4(
    const int*   __restrict__ seg_val,   // [N]
    const int*   __restrict__ seg_len,   // [N+1]
    const float* __restrict__ logit,     // [N]
    const float* __restrict__ ratio,     // [kNumInterval+1] (ws)
    float*       __restrict__ out_pred,  // [N]
    float*       __restrict__ out_bin,   // [N]
    int n)
{
    const float lpw  = ratio[kNumInterval];
    const int   tid  = threadIdx.x;
    const int   lane = tid & 63;
    const long  blockBase = (long)blockIdx.x * 2048;

    if (blockBase + 2048 <= (long)n) {
        const long e0 = blockBase + (long)tid * 4;
        const long e1 = e0 + 1024;

        // ---- issue all wave-coalesced stream loads up front ----
        const f32x4 L0 = __builtin_nontemporal_load((const f32x4*)(logit   + e0));
        const f32x4 L1 = __builtin_nontemporal_load((const f32x4*)(logit   + e1));
        const i32x4 S0 = __builtin_nontemporal_load((const i32x4*)(seg_len + e0));
        const i32x4 S1 = __builtin_nontemporal_load((const i32x4*)(seg_len + e1));

        // overlap value s[e+4] = next lane's s.x (lane 63: 1-lane load)
        int s0e = __shfl(S0.x, lane + 1);
        int s1e = __shfl(S1.x, lane + 1);
        if (lane == 63) {
            s0e = seg_len[e0 + 4];
            s1e = seg_len[e1 + 4];
        }

        const float l0[4] = {L0[0], L0[1], L0[2], L0[3]};
        const float l1[4] = {L1[0], L1[1], L1[2], L1[3]};
        const int   s0[5] = {S0[0], S0[1], S0[2], S0[3], s0e};
        const int   s1[5] = {S1[0], S1[1], S1[2], S1[3], s1e};

        f32x4 op0, ob0, op1, ob1;
        process4(l0, s0, seg_val, ratio, lpw, (float*)&op0, (float*)&ob0);
        process4(l1, s1, seg_val, ratio, lpw, (float*)&op1, (float*)&ob1);

        __builtin_nontemporal_store(op0, (f32x4*)(out_pred + e0));
        __builtin_nontemporal_store(op1, (f32x4*)(out_pred + e1));
        __builtin_nontemporal_store(ob0, (f32x4*)(out_bin  + e0));
        __builtin_nontemporal_store(ob1, (f32x4*)(out_bin  + e1));
    } else {
        // tail block: scalar, bounds-checked (only the last block)
        const float kStep = 0.0002f;
        for (long i = blockBase + tid; i < (long)n; i += 256) {
            const float x  = logit[i] + lpw;
            const float pf = 1.0f / (1.0f + expf(-x));
            int d = 0;
            if (seg_len[i + 1] > seg_len[i]) {
                const int sv = seg_val[seg_len[i]] + 1;
                d = (sv > kNumSegments) ? 0 : sv;
            }
            const int bin = (int)(ceilf(pf / kStep) - 1.0f) + d * kNumBins;
            int idx = bin < 0 ? 0 : (bin > kNumInterval - 1 ? kNumInterval - 1 : bin);
            const float rr = ratio[idx];
            out_pred[i] = (rr == rr) ? (rr + pf * 0.0005f) : pf;
            out_bin[i]  = (float)bin;
        }
    }
}

// Fallback if ws is too small: direct two-table version, same layout idea.
__global__ __launch_bounds__(256) void hbc_direct(
    const int*   __restrict__ seg_val,
    const int*   __restrict__ seg_len,
    const float* __restrict__ logit,
    const float* __restrict__ bin_pos,
    const float* __restrict__ bin_num,
    const float* __restrict__ pos_w,
    float*       __restrict__ out_pred,
    float*       __restrict__ out_bin,
    int n)
{
    const float kStep = 0.0002f;
    const float lpw = logf(pos_w[0]);
    for (long i = (long)blockIdx.x * blockDim.x + threadIdx.x; i < (long)n;
         i += (long)gridDim.x * blockDim.x) {
        const float x  = logit[i] + lpw;
        const float pf = 1.0f / (1.0f + expf(-x));
        int d = 0;
        if (seg_len[i + 1] > seg_len[i]) {
            const int sv = seg_val[seg_len[i]] + 1;
            d = (sv > kNumSegments) ? 0 : sv;
        }
        const int bin = (int)(ceilf(pf / kStep) - 1.0f) + d * kNumBins;
        int idx = bin < 0 ? 0 : (bin > kNumInterval - 1 ? kNumInterval - 1 : bin);
        const float cp = bin_pos[idx];
        const float cn = bin_num[idx];
        const float ctr = (cp / cn) * 0.9995f + pf * 0.0005f;
        out_pred[i] = (cn > 0.0f) ? ctr : pf;
        out_bin[i]  = (float)bin;
    }
}

extern "C" void kernel_launch(void* const* d_in, const int* in_sizes, int n_in,
                              void* d_out, int out_size, void* d_ws, size_t ws_size,
                              hipStream_t stream) {
    const int*   seg_val = (const int*)  d_in[0];
    const int*   seg_len = (const int*)  d_in[1];
    const float* logit   = (const float*)d_in[2];
    const float* bin_pos = (const float*)d_in[3];
    const float* bin_num = (const float*)d_in[4];
    const float* pos_w   = (const float*)d_in[5];

    const int n = in_sizes[2];
    float* out_pred = (float*)d_out;
    float* out_bin  = (float*)d_out + n;

    const size_t ws_needed = (size_t)(kNumInterval + 1) * sizeof(float);
    const int threads = 256;

    if (ws_size >= ws_needed) {
        float* ratio = (float*)d_ws;
        const int blocks_prep = (kNumInterval + threads - 1) / threads;
        ratio_kernel<<<blocks_prep, threads, 0, stream>>>(bin_pos, bin_num, pos_w, ratio);
        const int blocks_main = (int)(((long)n + 2047) / 2048);
        hbc_lane4<<<blocks_main, threads, 0, stream>>>(
            seg_val, seg_len, logit, ratio, out_pred, out_bin, n);
    } else {
        int blocks = (int)(((long)n + threads - 1) / threads);
        if (blocks > 4096) blocks = 4096;
        hbc_direct<<<blocks, threads, 0, stream>>>(
            seg_val, seg_len, logit, bin_pos, bin_num, pos_w, out_pred, out_bin, n);
    }
}

// Round 7
// 336.628 us; speedup vs baseline: 1.1630x; 1.1630x over previous
//
#include <hip/hip_runtime.h>
#include <math.h>

// HistogramBinningCalibrationByFeature
// d_out: [0..N) calibrated_prediction (f32) | [N..2N) bin ids (f32-encoded)
//
// R4..R7 (resubmits after infra timeouts): the divergent calibration gather
// moves from global (TCP tag-serialized, ~64 lines/wave-instr) into LDS.
// Table = fused ratio (pos/num)*0.9995 quantized to 4-bit codes (0..14;
// 15=invalid) -> 215000 nibbles = 107.5 KB LDS per block. 1024-thread
// blocks, 1 block/CU, grid-stride over 8192-elem tiles, 8 elems/thread,
// lane-interleaved coalesced streams.

constexpr int kNumBins     = 5000;
constexpr int kNumSegments = 42;
constexpr int kNumInterval = (kNumSegments + 1) * kNumBins;  // 215000
constexpr int kWords       = kNumInterval / 8;               // 26875 packed u32
constexpr int kLpwWord     = kWords;                         // lpw stored after

typedef float f32x4 __attribute__((ext_vector_type(4)));
typedef int   i32x4 __attribute__((ext_vector_type(4)));

__global__ __launch_bounds__(256) void pack_kernel(
    const float* __restrict__ bin_pos,
    const float* __restrict__ bin_num,
    const float* __restrict__ pos_w,
    unsigned int* __restrict__ packed)   // [kWords + 1] in d_ws
{
    const int w = blockIdx.x * 256 + threadIdx.x;
    if (w < kWords) {
        unsigned int word = 0;
        #pragma unroll
        for (int j = 0; j < 8; ++j) {
            const int i = w * 8 + j;
            const float nm = bin_num[i];
            unsigned int code = 15u;                 // invalid sentinel
            if (nm > 0.0f) {
                const float r = (bin_pos[i] / nm) * 0.9995f;   // in [0, 0.9995]
                int c = (int)(r * 14.0f + 0.5f);
                c = c < 0 ? 0 : (c > 14 ? 14 : c);
                code = (unsigned int)c;
            }
            word |= code << (j * 4);
        }
        packed[w] = word;
    }
    if (w == 0) {
        packed[kLpwWord] = __float_as_uint((float)log((double)pos_w[0]));
    }
}

__device__ __forceinline__ void process4_lds(
    const float* __restrict__ l, const int* __restrict__ s,
    const int* __restrict__ seg_val, const unsigned int* __restrict__ tab,
    float lpw, float* __restrict__ op, float* __restrict__ ob)
{
    constexpr float kInvStep = 1.0f / 0.0002f;

    int ds[4];
    #pragma unroll
    for (int j = 0; j < 4; ++j) {
        int d = 0;
        if (s[j + 1] > s[j]) {                     // predicated gather
            const int sv = seg_val[s[j]] + 1;
            d = (sv > kNumSegments) ? 0 : sv;
        }
        ds[j] = d;
    }

    float p[4]; int bin[4];
    #pragma unroll
    for (int j = 0; j < 4; ++j) {
        const float x  = l[j] + lpw;
        const float e  = __expf(-x);               // v_exp_f32 path
        const float pf = __builtin_amdgcn_rcpf(1.0f + e);
        p[j]   = pf;
        bin[j] = (int)(__builtin_ceilf(pf * kInvStep) - 1.0f) + ds[j] * kNumBins;
    }

    unsigned int wd[4]; int sh[4];
    #pragma unroll
    for (int j = 0; j < 4; ++j) {
        int idx = bin[j];
        idx = idx < 0 ? 0 : idx;
        idx = idx > (kNumInterval - 1) ? (kNumInterval - 1) : idx;
        wd[j] = tab[idx >> 3];                     // random LDS read
        sh[j] = (idx & 7) << 2;
    }

    #pragma unroll
    for (int j = 0; j < 4; ++j) {
        const unsigned int code = (wd[j] >> sh[j]) & 15u;
        const float r = (float)code * (1.0f / 14.0f);
        op[j] = (code == 15u) ? p[j] : fmaf(p[j], 0.0005f, r);
        ob[j] = (float)bin[j];
    }
}

__global__ __launch_bounds__(1024, 4) void hbc_lds(
    const int*          __restrict__ seg_val,   // [N]
    const int*          __restrict__ seg_len,   // [N+1]
    const float*        __restrict__ logit,     // [N]
    const unsigned int* __restrict__ packed,    // [kWords+1] (ws)
    float*              __restrict__ out_pred,  // [N]
    float*              __restrict__ out_bin,   // [N]
    int n)
{
    __shared__ unsigned int tab[26880];          // 107520 B

    const int tid  = threadIdx.x;
    const int lane = tid & 63;

    for (int w = tid; w < kWords; w += 1024)     // stage table once per block
        tab[w] = packed[w];
    const float lpw = __uint_as_float(packed[kLpwWord]);
    __syncthreads();

    const long  ntiles = (long)n >> 13;          // full 8192-elem tiles
    for (long tile = blockIdx.x; tile < ntiles; tile += gridDim.x) {
        const long base = tile << 13;
        const long e0 = base + (long)tid * 4;
        const long e1 = e0 + 4096;

        const f32x4 L0 = __builtin_nontemporal_load((const f32x4*)(logit   + e0));
        const f32x4 L1 = __builtin_nontemporal_load((const f32x4*)(logit   + e1));
        const i32x4 S0 = __builtin_nontemporal_load((const i32x4*)(seg_len + e0));
        const i32x4 S1 = __builtin_nontemporal_load((const i32x4*)(seg_len + e1));

        int s0e = __shfl(S0.x, lane + 1);        // next lane's first s
        int s1e = __shfl(S1.x, lane + 1);
        if (lane == 63) {
            s0e = seg_len[e0 + 4];
            s1e = seg_len[e1 + 4];
        }

        const float l0[4] = {L0[0], L0[1], L0[2], L0[3]};
        const float l1[4] = {L1[0], L1[1], L1[2], L1[3]};
        const int   s0[5] = {S0[0], S0[1], S0[2], S0[3], s0e};
        const int   s1[5] = {S1[0], S1[1], S1[2], S1[3], s1e};

        f32x4 op0, ob0, op1, ob1;
        process4_lds(l0, s0, seg_val, tab, lpw, (float*)&op0, (float*)&ob0);
        process4_lds(l1, s1, seg_val, tab, lpw, (float*)&op1, (float*)&ob1);

        __builtin_nontemporal_store(op0, (f32x4*)(out_pred + e0));
        __builtin_nontemporal_store(op1, (f32x4*)(out_pred + e1));
        __builtin_nontemporal_store(ob0, (f32x4*)(out_bin  + e0));
        __builtin_nontemporal_store(ob1, (f32x4*)(out_bin  + e1));
    }

    // tail (N % 8192 elements), scalar + bounds-checked
    constexpr float kInvStep = 1.0f / 0.0002f;
    const long tailStart = ntiles << 13;
    for (long i = tailStart + (long)blockIdx.x * 1024 + tid; i < (long)n;
         i += (long)gridDim.x * 1024) {
        const float x  = logit[i] + lpw;
        const float pf = __builtin_amdgcn_rcpf(1.0f + __expf(-x));
        int d = 0;
        if (seg_len[i + 1] > seg_len[i]) {
            const int sv = seg_val[seg_len[i]] + 1;
            d = (sv > kNumSegments) ? 0 : sv;
        }
        const int bin = (int)(__builtin_ceilf(pf * kInvStep) - 1.0f) + d * kNumBins;
        int idx = bin < 0 ? 0 : (bin > kNumInterval - 1 ? kNumInterval - 1 : bin);
        const unsigned int code = (tab[idx >> 3] >> ((idx & 7) << 2)) & 15u;
        const float r = (float)code * (1.0f / 14.0f);
        out_pred[i] = (code == 15u) ? pf : fmaf(pf, 0.0005f, r);
        out_bin[i]  = (float)bin;
    }
}

// Fallback if ws is too small: direct two-table global-gather version.
__global__ __launch_bounds__(256) void hbc_direct(
    const int*   __restrict__ seg_val,
    const int*   __restrict__ seg_len,
    const float* __restrict__ logit,
    const float* __restrict__ bin_pos,
    const float* __restrict__ bin_num,
    const float* __restrict__ pos_w,
    float*       __restrict__ out_pred,
    float*       __restrict__ out_bin,
    int n)
{
    const float kStep = 0.0002f;
    const float lpw = logf(pos_w[0]);
    for (long i = (long)blockIdx.x * blockDim.x + threadIdx.x; i < (long)n;
         i += (long)gridDim.x * blockDim.x) {
        const float x  = logit[i] + lpw;
        const float pf = 1.0f / (1.0f + expf(-x));
        int d = 0;
        if (seg_len[i + 1] > seg_len[i]) {
            const int sv = seg_val[seg_len[i]] + 1;
            d = (sv > kNumSegments) ? 0 : sv;
        }
        const int bin = (int)(ceilf(pf / kStep) - 1.0f) + d * kNumBins;
        int idx = bin < 0 ? 0 : (bin > kNumInterval - 1 ? kNumInterval - 1 : bin);
        const float cp = bin_pos[idx];
        const float cn = bin_num[idx];
        const float ctr = (cp / cn) * 0.9995f + pf * 0.0005f;
        out_pred[i] = (cn > 0.0f) ? ctr : pf;
        out_bin[i]  = (float)bin;
    }
}

extern "C" void kernel_launch(void* const* d_in, const int* in_sizes, int n_in,
                              void* d_out, int out_size, void* d_ws, size_t ws_size,
                              hipStream_t stream) {
    const int*   seg_val = (const int*)  d_in[0];
    const int*   seg_len = (const int*)  d_in[1];
    const float* logit   = (const float*)d_in[2];
    const float* bin_pos = (const float*)d_in[3];
    const float* bin_num = (const float*)d_in[4];
    const float* pos_w   = (const float*)d_in[5];

    const int n = in_sizes[2];
    float* out_pred = (float*)d_out;
    float* out_bin  = (float*)d_out + n;

    const size_t ws_needed = (size_t)(kWords + 1) * sizeof(unsigned int);

    if (ws_size >= ws_needed) {
        unsigned int* packed = (unsigned int*)d_ws;
        const int blocks_prep = (kWords + 255) / 256;
        pack_kernel<<<blocks_prep, 256, 0, stream>>>(bin_pos, bin_num, pos_w, packed);
        hbc_lds<<<512, 1024, 0, stream>>>(
            seg_val, seg_len, logit, packed, out_pred, out_bin, n);
    } else {
        int blocks = (int)(((long)n + 255) / 256);
        if (blocks > 4096) blocks = 4096;
        hbc_direct<<<blocks, 256, 0, stream>>>(
            seg_val, seg_len, logit, bin_pos, bin_num, pos_w, out_pred, out_bin, n);
    }
}